// Round 1
// baseline (17786.087 us; speedup 1.0000x reference)
//
#include <hip/hip_runtime.h>

#define NN 512
#define TSTEPS 1200
#define BATCH 128
#define TB (TSTEPS * BATCH)   // 153600

typedef __attribute__((ext_vector_type(8))) short bf16x8;
typedef __attribute__((ext_vector_type(4))) float f32x4;

__device__ __forceinline__ unsigned short f2bf(float x) {
    unsigned u = __float_as_uint(x);
    u += 0x7fffu + ((u >> 16) & 1u);   // round-to-nearest-even
    return (unsigned short)(u >> 16);
}
__device__ __forceinline__ float bf2f(unsigned short h) {
    return __uint_as_float(((unsigned)h) << 16);
}

// Grid: 256 WGs = 32 n-groups x 8 batch-groups. bg in LOW bits of blockIdx so
// that all 32 WGs of one batch-group land on the same XCD (blockIdx % 8 swizzle)
// -> barrier atomics + state exchange stay XCD-L2-local.
__global__ __launch_bounds__(256)
void rnn_kernel(const float* __restrict__ u, const float* __restrict__ Wrec,
                const float* __restrict__ Winp, const float* __restrict__ Wout,
                const float* __restrict__ yinit, const float* __restrict__ rnoise,
                const float* __restrict__ inoise, float* __restrict__ states,
                float* __restrict__ outs, unsigned* __restrict__ cnt)
{
    __shared__ unsigned short sWh[16][520] __attribute__((aligned(16)));
    __shared__ unsigned short sWl[16][520] __attribute__((aligned(16)));
    __shared__ unsigned short sSh[16][520] __attribute__((aligned(16)));
    __shared__ unsigned short sSl[16][520] __attribute__((aligned(16)));
    __shared__ float red[4][256];
    __shared__ float uin[6][16];
    __shared__ float winp[16][6];

    const int blk = blockIdx.x;
    const int bg  = blk & 7;     // batch group (XCD-local)
    const int ng  = blk >> 3;    // n group
    const int tid = threadIdx.x;
    const int b0  = bg * 16;
    const int n0  = ng * 16;

    // ---- W_rec tile -> LDS as bf16 hi/lo (persistent across all steps) ----
    {
        int r  = tid >> 4;
        int kc = (tid & 15) * 32;
        const float* wrow = Wrec + (size_t)(n0 + r) * NN + kc;
        #pragma unroll
        for (int j = 0; j < 32; j += 4) {
            float4 v = *(const float4*)(wrow + j);
            int k = kc + j;
            unsigned short h0 = f2bf(v.x), h1 = f2bf(v.y), h2 = f2bf(v.z), h3 = f2bf(v.w);
            sWh[r][k] = h0; sWh[r][k+1] = h1; sWh[r][k+2] = h2; sWh[r][k+3] = h3;
            sWl[r][k]   = f2bf(v.x - bf2f(h0));
            sWl[r][k+1] = f2bf(v.y - bf2f(h1));
            sWl[r][k+2] = f2bf(v.z - bf2f(h2));
            sWl[r][k+3] = f2bf(v.w - bf2f(h3));
        }
    }
    if (tid < 96) {  // W_inp tile: 16 n x 6
        int nn = tid / 6, i = tid % 6;
        winp[nn][i] = Winp[(size_t)(n0 + nn) * 6 + i];
    }

    // ---- init states[:,0,:] for this bg's batches (redundant across ng; identical values) ----
    {
        int b = tid & 15, k0 = tid >> 4;
        #pragma unroll 8
        for (int j = 0; j < 32; ++j) {
            int k = j * 16 + k0;
            states[(size_t)k * TB + b0 + b] = yinit[k];
        }
    }
    __syncthreads();

    const int lane = tid & 63;
    const int wv   = tid >> 6;        // wave id: K-split 4 ways
    const int lrow = lane & 15;       // m (batch) for A-frag, n for B-frag, col for D
    const int lq   = lane >> 4;       // quad
    unsigned* myCnt = cnt + bg * 32;  // 128-B spaced counters

    // epilogue thread mapping (one output element per thread)
    const int bb = tid & 15;          // batch within tile (coalesced dim)
    const int nn = tid >> 4;          // n within tile
    // running state s_t[b0+bb][n0+nn] carried in a register across steps
    float scur = yinit[n0 + nn];

    for (int t = 0; t < TSTEPS - 1; ++t) {
        const size_t toff = (size_t)t * BATCH;
        // prefetch rec_noise for this step's epilogue (hide HBM latency)
        const size_t eoff = (size_t)(n0 + nn) * TB + toff + b0 + bb;
        float rn = rnoise[eoff];

        // ---- stage s_t -> LDS hi/lo (reads states[:, t, b-tile], L2-local) ----
        {
            int b = tid & 15, k0 = tid >> 4;
            const float* src = states + toff + b0 + b;
            #pragma unroll 8
            for (int j = 0; j < 32; ++j) {
                int k = j * 16 + k0;
                float x = src[(size_t)k * TB];
                unsigned short h = f2bf(x);
                sSh[b][k] = h;
                sSl[b][k] = f2bf(x - bf2f(h));
            }
        }
        if (tid < 96) {  // (u + inp_noise)[i, t, b-tile]
            int i = tid >> 4, b = tid & 15;
            size_t off = (size_t)i * TB + toff + b0 + b;
            uin[i][b] = u[off] + inoise[off];
        }
        __syncthreads();

        // ---- MFMA: acc[16b x 16n] = s @ Wrec_slice^T, K split across 4 waves ----
        f32x4 acc = {0.f, 0.f, 0.f, 0.f};
        #pragma unroll
        for (int it = 0; it < 4; ++it) {
            int k = wv * 128 + it * 32 + lq * 8;
            bf16x8 ah = *(const bf16x8*)&sSh[lrow][k];
            bf16x8 al = *(const bf16x8*)&sSl[lrow][k];
            bf16x8 bh = *(const bf16x8*)&sWh[lrow][k];
            bf16x8 bl = *(const bf16x8*)&sWl[lrow][k];
            acc = __builtin_amdgcn_mfma_f32_16x16x32_bf16(ah, bh, acc, 0, 0, 0);
            acc = __builtin_amdgcn_mfma_f32_16x16x32_bf16(ah, bl, acc, 0, 0, 0);
            acc = __builtin_amdgcn_mfma_f32_16x16x32_bf16(al, bh, acc, 0, 0, 0);
        }
        #pragma unroll
        for (int r = 0; r < 4; ++r)
            red[wv][(lq * 4 + r) * 16 + lrow] = acc[r];
        __syncthreads();

        // ---- epilogue: reduce K-partials, input term, tanh, state update ----
        {
            int idx = bb * 16 + nn;
            float pre = red[0][idx] + red[1][idx] + red[2][idx] + red[3][idx];
            #pragma unroll
            for (int i = 0; i < 6; ++i) pre += uin[i][bb] * winp[nn][i];
            scur = 0.9f * scur + 0.1f * (tanhf(pre) + rn);
            states[eoff + BATCH] = scur;   // states[n, t+1, b]
        }

        // ---- bg-local barrier: 32 WGs, monotonic counter ----
        if (tid == 0) {
            __threadfence();
            __hip_atomic_fetch_add(myCnt, 1u, __ATOMIC_RELEASE, __HIP_MEMORY_SCOPE_AGENT);
            unsigned target = 32u * (unsigned)(t + 1);
            while (__hip_atomic_load(myCnt, __ATOMIC_ACQUIRE, __HIP_MEMORY_SCOPE_AGENT) < target)
                __builtin_amdgcn_s_sleep(2);
        }
        __syncthreads();
    }

    // ---- outputs[o, t, b] = sum_n Wout[o,n] * states[n, t, b] for our bg ----
    // 1200*16 = 19200 items per bg, split across the 32 ng-WGs; 75 chunks of 256.
    for (int c = ng; c < 75; c += 32) {
        int item = c * 256 + tid;
        int t  = item >> 4;
        int b  = item & 15;
        size_t base = (size_t)t * BATCH + b0 + b;
        float a0 = 0.f, a1 = 0.f;
        #pragma unroll 8
        for (int n = 0; n < NN; ++n) {
            float s = states[(size_t)n * TB + base];
            a0 += Wout[n] * s;
            a1 += Wout[NN + n] * s;
        }
        outs[base] = a0;
        outs[TB + base] = a1;
    }
}

extern "C" void kernel_launch(void* const* d_in, const int* in_sizes, int n_in,
                              void* d_out, int out_size, void* d_ws, size_t ws_size,
                              hipStream_t stream) {
    const float* u     = (const float*)d_in[0];
    const float* Wrec  = (const float*)d_in[1];
    const float* Winp  = (const float*)d_in[2];
    const float* Wout  = (const float*)d_in[3];
    const float* yinit = (const float*)d_in[4];
    const float* rn    = (const float*)d_in[5];
    const float* in_   = (const float*)d_in[6];
    float* states = (float*)d_out;
    float* outs   = states + (size_t)NN * TSTEPS * BATCH;
    unsigned* cnt = (unsigned*)d_ws;

    // barrier counters must start at 0 (ws is poisoned 0xAA before every launch)
    hipMemsetAsync(d_ws, 0, 8 * 32 * sizeof(unsigned), stream);

    void* args[] = {&u, &Wrec, &Winp, &Wout, &yinit, &rn, &in_, &states, &outs, &cnt};
    hipLaunchCooperativeKernel(reinterpret_cast<void*>(rnn_kernel),
                               dim3(256), dim3(256), args, 0, stream);
}

// Round 2
// 4278.595 us; speedup vs baseline: 4.1570x; 4.1570x over previous
//
#include <hip/hip_runtime.h>

#define NN 512
#define TSTEPS 1200
#define BATCH 128
#define TB (TSTEPS * BATCH)   // 153600

typedef __attribute__((ext_vector_type(8))) short bf16x8;
typedef __attribute__((ext_vector_type(8))) unsigned short u16x8;
typedef __attribute__((ext_vector_type(4))) float f32x4;

__device__ __forceinline__ unsigned short f2bf(float x) {
    unsigned u = __float_as_uint(x);
    u += 0x7fffu + ((u >> 16) & 1u);   // round-to-nearest-even
    return (unsigned short)(u >> 16);
}
__device__ __forceinline__ float bf2f(unsigned short h) {
    return __uint_as_float(((unsigned)h) << 16);
}
// Relaxed agent-scope atomics: point-of-coherence (Infinity Cache) access with
// NO buffer_wbl2/buffer_inv fence instructions. Correct for cross-XCD exchange
// independent of WG->XCD mapping.
__device__ __forceinline__ float aload(const float* p) {
    unsigned u = __hip_atomic_load((const unsigned*)p, __ATOMIC_RELAXED, __HIP_MEMORY_SCOPE_AGENT);
    return __uint_as_float(u);
}
__device__ __forceinline__ void astore(float* p, float v) {
    __hip_atomic_store((unsigned*)p, __float_as_uint(v), __ATOMIC_RELAXED, __HIP_MEMORY_SCOPE_AGENT);
}

// Grid: 256 WGs = 32 n-groups x 8 batch-groups.
__global__ __launch_bounds__(256)
void rnn_kernel(const float* __restrict__ u, const float* __restrict__ Wrec,
                const float* __restrict__ Winp, const float* __restrict__ Wout,
                const float* __restrict__ yinit, const float* __restrict__ rnoise,
                const float* __restrict__ inoise, float* __restrict__ states,
                float* __restrict__ outs, unsigned* __restrict__ flags)
{
    __shared__ unsigned short sWh[16][520] __attribute__((aligned(16)));
    __shared__ unsigned short sWl[16][520] __attribute__((aligned(16)));
    __shared__ unsigned short sSh[16][520] __attribute__((aligned(16)));
    __shared__ unsigned short sSl[16][520] __attribute__((aligned(16)));
    __shared__ float red[4][256];
    __shared__ float uin[6][16];
    __shared__ float winp[16][6];

    const int blk = blockIdx.x;
    const int bg  = blk & 7;     // batch group
    const int ng  = blk >> 3;    // n group
    const int tid = threadIdx.x;
    const int b0  = bg * 16;
    const int n0  = ng * 16;

    // ---- W_rec tile -> LDS as bf16 hi/lo (persistent across all steps) ----
    {
        int r  = tid >> 4;
        int kc = (tid & 15) * 32;
        const float* wrow = Wrec + (size_t)(n0 + r) * NN + kc;
        #pragma unroll
        for (int j = 0; j < 32; j += 4) {
            float4 v = *(const float4*)(wrow + j);
            int k = kc + j;
            unsigned short h0 = f2bf(v.x), h1 = f2bf(v.y), h2 = f2bf(v.z), h3 = f2bf(v.w);
            sWh[r][k] = h0; sWh[r][k+1] = h1; sWh[r][k+2] = h2; sWh[r][k+3] = h3;
            sWl[r][k]   = f2bf(v.x - bf2f(h0));
            sWl[r][k+1] = f2bf(v.y - bf2f(h1));
            sWl[r][k+2] = f2bf(v.z - bf2f(h2));
            sWl[r][k+3] = f2bf(v.w - bf2f(h3));
        }
    }
    if (tid < 96) {  // W_inp tile: 16 n x 6
        int nn = tid / 6, i = tid % 6;
        winp[nn][i] = Winp[(size_t)(n0 + nn) * 6 + i];
    }

    // ---- init states[:,0,:] for this bg's b-tile via MALL-visible stores ----
    {
        int b = tid & 15, k0 = tid >> 4;
        #pragma unroll 8
        for (int j = 0; j < 32; ++j) {
            int k = j * 16 + k0;
            astore(&states[(size_t)k * TB + b0 + b], yinit[k]);
        }
    }
    __syncthreads();   // also drains vmcnt for all waves -> init visible at MALL

    const int lane = tid & 63;
    const int wv   = tid >> 6;        // wave id: K-split 4 ways
    const int lrow = lane & 15;
    const int lq   = lane >> 4;

    // epilogue thread mapping (one output element per thread)
    const int bb = tid & 15;          // batch within tile
    const int nn = tid >> 4;          // n within tile
    float scur = yinit[n0 + nn];

    // staging thread mapping
    const int sb = tid & 15;          // batch row
    const int kc = (tid >> 4) * 32;   // k chunk (32 consecutive k)

    for (int t = 0; t < TSTEPS - 1; ++t) {
        const size_t toff = (size_t)t * BATCH;
        const size_t eoff = (size_t)(n0 + nn) * TB + toff + b0 + bb;
        float rn = rnoise[eoff];   // plain load (read-only input), issued early

        if (tid < 96) {  // (u + inp_noise)[i, t, b-tile]
            int i = tid >> 4, b = tid & 15;
            size_t off = (size_t)i * TB + toff + b0 + b;
            uin[i][b] = u[off] + inoise[off];
        }

        // ---- stage s_t -> LDS hi/lo; reads via MALL (coherence point) ----
        {
            const float* src = states + toff + b0 + sb;
            float v[32];
            #pragma unroll
            for (int j = 0; j < 32; ++j)
                v[j] = aload(src + (size_t)(kc + j) * TB);
            #pragma unroll
            for (int c = 0; c < 4; ++c) {
                u16x8 hv, lv;
                #pragma unroll
                for (int e = 0; e < 8; ++e) {
                    float x = v[c * 8 + e];
                    unsigned short h = f2bf(x);
                    hv[e] = h;
                    lv[e] = f2bf(x - bf2f(h));
                }
                *(u16x8*)&sSh[sb][kc + c * 8] = hv;   // ds_write_b128
                *(u16x8*)&sSl[sb][kc + c * 8] = lv;
            }
        }
        __syncthreads();

        // ---- MFMA: acc[16b x 16n] = s @ Wrec_slice^T, K split across 4 waves ----
        f32x4 acc = {0.f, 0.f, 0.f, 0.f};
        #pragma unroll
        for (int it = 0; it < 4; ++it) {
            int k = wv * 128 + it * 32 + lq * 8;
            bf16x8 ah = *(const bf16x8*)&sSh[lrow][k];
            bf16x8 al = *(const bf16x8*)&sSl[lrow][k];
            bf16x8 bh = *(const bf16x8*)&sWh[lrow][k];
            bf16x8 bl = *(const bf16x8*)&sWl[lrow][k];
            acc = __builtin_amdgcn_mfma_f32_16x16x32_bf16(ah, bh, acc, 0, 0, 0);
            acc = __builtin_amdgcn_mfma_f32_16x16x32_bf16(ah, bl, acc, 0, 0, 0);
            acc = __builtin_amdgcn_mfma_f32_16x16x32_bf16(al, bh, acc, 0, 0, 0);
        }
        // contiguous per-lane store: red[wv][n_local*16 + batch_local]
        {
            f32x4 rv = acc;
            *(f32x4*)&red[wv][lrow * 16 + lq * 4] = rv;   // ds_write_b128
        }
        __syncthreads();

        // ---- epilogue: reduce K-partials, input term, tanh, state update ----
        {
            int idx = nn * 16 + bb;
            float pre = red[0][idx] + red[1][idx] + red[2][idx] + red[3][idx];
            #pragma unroll
            for (int i = 0; i < 6; ++i) pre += uin[i][bb] * winp[nn][i];
            scur = 0.9f * scur + 0.1f * (tanhf(pre) + rn);
            astore(&states[eoff + BATCH], scur);   // states[n, t+1, b] -> MALL
        }
        __syncthreads();   // every wave drains vmcnt(0) -> all 256 stores at MALL

        // ---- bg-local barrier: per-WG monotonic flags, no fences ----
        if (tid == 0)
            __hip_atomic_store(&flags[bg * 32 + ng], (unsigned)(t + 1),
                               __ATOMIC_RELAXED, __HIP_MEMORY_SCOPE_AGENT);
        if (tid < 64) {
            unsigned slot = bg * 32 + (tid & 31);
            while (__hip_atomic_load(&flags[slot], __ATOMIC_RELAXED,
                                     __HIP_MEMORY_SCOPE_AGENT) < (unsigned)(t + 1)) {
            }
        }
        __syncthreads();
    }

    // ---- outputs[o, t, b] = sum_n Wout[o,n] * states[n, t, b] for our bg ----
    for (int c = ng; c < 75; c += 32) {
        int item = c * 256 + tid;
        int t  = item >> 4;
        int b  = item & 15;
        size_t base = (size_t)t * BATCH + b0 + b;
        float a0 = 0.f, a1 = 0.f;
        #pragma unroll 8
        for (int n = 0; n < NN; ++n) {
            float s = states[(size_t)n * TB + base];
            a0 += Wout[n] * s;
            a1 += Wout[NN + n] * s;
        }
        outs[base] = a0;
        outs[TB + base] = a1;
    }
}

extern "C" void kernel_launch(void* const* d_in, const int* in_sizes, int n_in,
                              void* d_out, int out_size, void* d_ws, size_t ws_size,
                              hipStream_t stream) {
    const float* u     = (const float*)d_in[0];
    const float* Wrec  = (const float*)d_in[1];
    const float* Winp  = (const float*)d_in[2];
    const float* Wout  = (const float*)d_in[3];
    const float* yinit = (const float*)d_in[4];
    const float* rn    = (const float*)d_in[5];
    const float* in_   = (const float*)d_in[6];
    float* states = (float*)d_out;
    float* outs   = states + (size_t)NN * TSTEPS * BATCH;
    unsigned* flags = (unsigned*)d_ws;

    // flags must start at 0 (ws is poisoned 0xAA before every launch)
    hipMemsetAsync(d_ws, 0, 256 * sizeof(unsigned), stream);

    void* args[] = {&u, &Wrec, &Winp, &Wout, &yinit, &rn, &in_, &states, &outs, &flags};
    hipLaunchCooperativeKernel(reinterpret_cast<void*>(rnn_kernel),
                               dim3(256), dim3(256), args, 0, stream);
}